// Round 1
// baseline (213.064 us; speedup 1.0000x reference)
//
#include <hip/hip_runtime.h>
#include <hip/hip_bf16.h>

// Problem constants (DeformableNCC)
constexpr int B_ = 64, K_ = 32, T_ = 1280, C_ = 16, E_ = 64;
constexpr int CC_ = 32, POOL_ = 10, TB_ = 128;           // conv channels, pool bins, t per bin
constexpr long long OUT_WARPED = (long long)B_ * K_ * T_ * C_;  // 41,943,040

// ---------------------------------------------------------------------------
// Kernel A: Conv1d(k=5,pad=2) + ReLU + avg-pool(128) for one (b, pool-bin).
// grid = B*POOL blocks x 256 threads. Output: pooled[b*320 + oc*10 + p].
// Thread mapping: oc = tid>>3 (32 ocs), tsub = tid&7; each thread covers
// tl in [tsub*16, tsub*16+16) within the bin, with a register-rolling
// 5-row input window (4 ds_read_b128 per output instead of 20).
// ---------------------------------------------------------------------------
__global__ __launch_bounds__(256) void conv_pool_k(
    const float* __restrict__ x,       // [B,T,C]
    const float* __restrict__ conv_w,  // [32,16,5]
    const float* __restrict__ conv_b,  // [32]
    float* __restrict__ pooled)        // [B,320]  (flatten order oc*10+p)
{
    const int blk = blockIdx.x;
    const int b = blk / POOL_;
    const int p = blk % POOL_;
    const int tid = threadIdx.x;

    // xs rows r = 0..131 correspond to global t = p*128 - 2 + r; stride 20
    // floats (pad: distinct banks across tsub, 16B-aligned rows).
    __shared__ float xs[132 * 20];
    // wt[oc*84 + kt*16 + ic]: transposed weights; stride 84 breaks oc-stride
    // bank conflicts (84*4 % 128B pattern -> distinct banks), 16B aligned.
    __shared__ float wt[32 * 84];
    __shared__ float part[256];

    // Stage transposed weights: conv_w flat [oc][ic][kt]
    for (int f = tid; f < CC_ * C_ * 5; f += 256) {
        int oc = f / 80, r = f % 80, ic = r / 5, kt = r % 5;
        wt[oc * 84 + kt * 16 + ic] = conv_w[f];
    }
    // Stage x window (zero padded outside [0,T))
    const float4* x4 = (const float4*)(x + (size_t)b * T_ * C_);
    for (int f = tid; f < 132 * 4; f += 256) {
        int row = f >> 2, c4 = f & 3;
        int t = p * TB_ - 2 + row;
        float4 v = make_float4(0.f, 0.f, 0.f, 0.f);
        if (t >= 0 && t < T_) v = x4[t * 4 + c4];
        *(float4*)(&xs[row * 20 + c4 * 4]) = v;
    }
    __syncthreads();

    const int oc = tid >> 3;
    const int tsub = tid & 7;

    // Hoist weights to registers: 5 kt x 4 float4 = 80 VGPRs
    float4 w[5][4];
#pragma unroll
    for (int kt = 0; kt < 5; ++kt)
#pragma unroll
        for (int c4 = 0; c4 < 4; ++c4)
            w[kt][c4] = *(const float4*)(&wt[oc * 84 + kt * 16 + c4 * 4]);
    const float bias = conv_b[oc];

    const int base = tsub * 16;  // first xs row this thread needs
    float4 win[5][4];
#pragma unroll
    for (int r = 0; r < 4; ++r)
#pragma unroll
        for (int c4 = 0; c4 < 4; ++c4)
            win[r][c4] = *(const float4*)(&xs[(base + r) * 20 + c4 * 4]);

    float local = 0.f;
#pragma unroll
    for (int jj = 0; jj < 16; ++jj) {
        const int ld = (jj + 4) % 5;
#pragma unroll
        for (int c4 = 0; c4 < 4; ++c4)
            win[ld][c4] = *(const float4*)(&xs[(base + jj + 4) * 20 + c4 * 4]);
        float acc = bias;
#pragma unroll
        for (int kt = 0; kt < 5; ++kt) {
            const float4* xv = win[(jj + kt) % 5];
#pragma unroll
            for (int c4 = 0; c4 < 4; ++c4) {
                acc += xv[c4].x * w[kt][c4].x;
                acc += xv[c4].y * w[kt][c4].y;
                acc += xv[c4].z * w[kt][c4].z;
                acc += xv[c4].w * w[kt][c4].w;
            }
        }
        local += fmaxf(acc, 0.f);
    }

    part[tid] = local;  // [oc][tsub]
    __syncthreads();
    if (tid < CC_) {
        float s = 0.f;
#pragma unroll
        for (int i = 0; i < 8; ++i) s += part[tid * 8 + i];
        pooled[b * (CC_ * POOL_) + tid * POOL_ + p] = s * (1.f / 128.f);
    }
}

// ---------------------------------------------------------------------------
// Kernel B: embed = relu(pooled @ lin_w.T + lin_b); warp/off heads.
// grid = B blocks x 64 threads (one wave).
// ---------------------------------------------------------------------------
__global__ __launch_bounds__(64) void heads_k(
    const float* __restrict__ pooled,  // [B,320]
    const float* __restrict__ lin_w,   // [64,320]
    const float* __restrict__ lin_b,   // [64]
    const float* __restrict__ warp_W,  // [32,64]
    const float* __restrict__ warp_b,  // [32]
    const float* __restrict__ off_W,   // [32,64]
    const float* __restrict__ off_b,   // [32]
    float* __restrict__ warp_s,        // [B*K] scratch
    float* __restrict__ off_s,         // [B*K] scratch
    float* __restrict__ out_tail)      // d_out + OUT_WARPED
{
    const int b = blockIdx.x;
    const int tid = threadIdx.x;
    __shared__ float4 ps4[80];
    __shared__ float emb[64];

    const float4* pin = (const float4*)(pooled + (size_t)b * 320);
    for (int i = tid; i < 80; i += 64) ps4[i] = pin[i];
    __syncthreads();

    // embed[tid]
    float acc = lin_b[tid];
    const float4* lw4 = (const float4*)(lin_w + (size_t)tid * 320);
#pragma unroll 4
    for (int i = 0; i < 80; ++i) {
        float4 a = ps4[i], w = lw4[i];
        acc += a.x * w.x + a.y * w.y + a.z * w.z + a.w * w.w;
    }
    emb[tid] = fmaxf(acc, 0.f);
    __syncthreads();

    const int k = tid & 31;
    const float* W = (tid < 32) ? warp_W : off_W;
    const float* bb = (tid < 32) ? warp_b : off_b;
    float a2 = bb[k];
#pragma unroll 8
    for (int e = 0; e < E_; ++e) a2 += emb[e] * W[k * E_ + e];

    if (tid < 32) {
        warp_s[b * K_ + k] = a2;
        out_tail[b * K_ + k] = a2;           // warp output [B,K,1]
    } else {
        off_s[b * K_ + k] = a2;
        out_tail[B_ * K_ + b * K_ + k] = a2; // off output [B,K,1]
    }
}

// ---------------------------------------------------------------------------
// Kernel C: warped[b,k,t,:] = lerp(proto[k,i0,:], proto[k,i1,:]) + off.
// 4 threads per (b,k,t) row, one float4 (16B) store per thread -> fully
// coalesced 1 KiB/wave stores. Prototypes (2.6 MB) stay L2-resident.
// grid = B*K*T*4/256 = 40960 blocks.
// ---------------------------------------------------------------------------
__global__ __launch_bounds__(256) void warp_interp_k(
    const float* __restrict__ proto,   // [K,T,C]
    const float* __restrict__ warp_s,  // [B*K]
    const float* __restrict__ off_s,   // [B*K]
    float* __restrict__ out)           // [B,K,T,C]
{
    const int n = blockIdx.x * 256 + threadIdx.x;  // < B*K*T*4, exact
    const int q = n & 3;
    const int row = n >> 2;        // b*K*T/T ... = b*K + k after /T
    const int t = row % T_;
    const int bk = row / T_;       // b*K + k
    const int k = bk & (K_ - 1);

    const float wv = warp_s[bk];
    const float ov = off_s[bk];

    float idx = fminf(fmaxf((float)t - wv, 0.f), (float)(T_ - 1));
    const float f0 = floorf(idx);
    const int i0 = (int)f0;
    const int i1 = min(i0 + 1, T_ - 1);
    const float fr = idx - f0;
    const float omf = 1.f - fr;

    const float4* p4 = (const float4*)proto;
    const float4 g0 = p4[(k * T_ + i0) * 4 + q];
    const float4 g1 = p4[(k * T_ + i1) * 4 + q];

    // match reference order: g = proto + off, out = g0*(1-fr) + g1*fr
    float4 r;
    r.x = (g0.x + ov) * omf + (g1.x + ov) * fr;
    r.y = (g0.y + ov) * omf + (g1.y + ov) * fr;
    r.z = (g0.z + ov) * omf + (g1.z + ov) * fr;
    r.w = (g0.w + ov) * omf + (g1.w + ov) * fr;

    ((float4*)out)[n] = r;
}

// ---------------------------------------------------------------------------
extern "C" void kernel_launch(void* const* d_in, const int* in_sizes, int n_in,
                              void* d_out, int out_size, void* d_ws, size_t ws_size,
                              hipStream_t stream) {
    const float* x       = (const float*)d_in[0];
    const float* proto   = (const float*)d_in[1];
    const float* conv_w  = (const float*)d_in[2];
    const float* conv_b  = (const float*)d_in[3];
    const float* lin_w   = (const float*)d_in[4];
    const float* lin_b   = (const float*)d_in[5];
    const float* warp_W  = (const float*)d_in[6];
    const float* warp_b  = (const float*)d_in[7];
    const float* off_W   = (const float*)d_in[8];
    const float* off_b   = (const float*)d_in[9];

    float* out = (float*)d_out;
    float* ws = (float*)d_ws;
    float* pooled = ws;                       // 64*320 = 20480 floats
    float* warp_s = ws + 20480;               // 2048 floats
    float* off_s  = ws + 20480 + 2048;        // 2048 floats

    conv_pool_k<<<dim3(B_ * POOL_), dim3(256), 0, stream>>>(x, conv_w, conv_b, pooled);
    heads_k<<<dim3(B_), dim3(64), 0, stream>>>(pooled, lin_w, lin_b, warp_W, warp_b,
                                               off_W, off_b, warp_s, off_s,
                                               out + OUT_WARPED);
    warp_interp_k<<<dim3((B_ * K_ * T_ * 4) / 256), dim3(256), 0, stream>>>(
        proto, warp_s, off_s, out);
}